// Round 8
// baseline (263.564 us; speedup 1.0000x reference)
//
#include <hip/hip_runtime.h>
#include <stdint.h>

#define MDIM 8192
#define NDIM 1536
#define KDIM 3072

#define NMB ((KDIM / 64) * (NDIM / 64))
#define NCVT ((MDIM * KDIM / 4) / 256)

typedef unsigned short u16;
typedef float  f32x4  __attribute__((ext_vector_type(4)));
typedef __bf16 bf16x8 __attribute__((ext_vector_type(8)));

__device__ __forceinline__ u16 f2bf(float f) {
    union { float f; unsigned int u; } v; v.f = f;
    unsigned int u = v.u;
    return (u16)((u + 0x7fffu + ((u >> 16) & 1u)) >> 16);  // RNE
}

// ---------------- fused prep (R0/R2-proven): make_b blocks, then cvt_x blocks ----------------
__global__ void prep_kernel(const float* __restrict__ w, const float* __restrict__ mask,
                            u16* __restrict__ Bt,
                            const float4* __restrict__ x, ushort4* __restrict__ xb) {
    const int t = threadIdx.x;
    if (blockIdx.x < NMB) {
        __shared__ float sw[64][65];
        const int kb = blockIdx.x % (KDIM / 64);
        const int nb = blockIdx.x / (KDIM / 64);
        const int k0 = kb * 64, n0 = nb * 64;
        {
            const int c4 = t & 15;
            const int r  = t >> 4;
#pragma unroll
            for (int rr = 0; rr < 4; ++rr) {
                int row = rr * 16 + r;
                float4 v = *(const float4*)&w[(size_t)(k0 + row) * NDIM + n0 + c4 * 4];
                sw[row][c4 * 4 + 0] = v.x;
                sw[row][c4 * 4 + 1] = v.y;
                sw[row][c4 * 4 + 2] = v.z;
                sw[row][c4 * 4 + 3] = v.w;
            }
        }
        __syncthreads();
        {
            const int n  = t >> 2;
            const int ks = (t & 3) * 16;
#pragma unroll
            for (int j = 0; j < 4; ++j) {
                int k = ks + j * 4;
                float4 mv = *(const float4*)&mask[(size_t)(n0 + n) * KDIM + k0 + k];
                ushort4 o;
                o.x = f2bf(mv.x * sw[k + 0][n]);
                o.y = f2bf(mv.y * sw[k + 1][n]);
                o.z = f2bf(mv.z * sw[k + 2][n]);
                o.w = f2bf(mv.w * sw[k + 3][n]);
                *(ushort4*)&Bt[(size_t)(n0 + n) * KDIM + k0 + k] = o;
            }
        }
    } else {
        int i = (blockIdx.x - NMB) * 256 + t;
        float4 v = x[i];
        ushort4 o;
        o.x = f2bf(v.x); o.y = f2bf(v.y); o.z = f2bf(v.z); o.w = f2bf(v.w);
        xb[i] = o;
    }
}

// ---------------- GEMM: two job classes, both R5 8-phase skeleton, 1 block/CU ----------------
// Skip jobs (256): R5-exact 256x128, 32 kt (K-skip: cls0 k [0,1024)u[1536,2560);
//   cls2 [512,1536)u[2048,3072)). Full jobs (256): 256x64, 48 kt linear (cls1 n-range
//   split in two BN=64 columns), same 8-MFMA-cluster shape.
// Packing at 1 block/CU: order [128F | 128S-cls0 | 128S-cls2 | 128F]. Round-1 full-CUs
// free at 24e -> take cls2 skips (56e); skip-CUs free at 32e -> take fulls (56e). 56e
// makespan vs R5's 64e. XCD banding by = (idx&7)*4 + ... in every group.
__device__ __forceinline__ void gload_lds16(const void* g, void* l) {
    __builtin_amdgcn_global_load_lds(
        (const __attribute__((address_space(1))) unsigned int*)g,
        (__attribute__((address_space(3))) unsigned int*)l, 16, 0, 0);
}

#define BARR  __builtin_amdgcn_s_barrier()
#define PRIO1 __builtin_amdgcn_s_setprio(1)
#define PRIO0 __builtin_amdgcn_s_setprio(0)
#define VM(n) asm volatile("s_waitcnt vmcnt(" #n ")" ::: "memory")

// ======== skip path: R5-verbatim (BM=256, BN=128, NT=32) ========
__device__ __forceinline__ void gemm_skip(const u16* __restrict__ Ag, const u16* __restrict__ Bg,
                                          const float* __restrict__ bias, float* __restrict__ C,
                                          u16* smem, int m0, int n0, int kb0, int kb1, int tid) {
    u16* sAb = smem;             // 4 planes x 256 x 32
    u16* sBb = smem + 32768;     // 4 planes x 128 x 32
    const int wv = tid >> 6, lane = tid & 63;
    const int srow = lane >> 2;
    const int scol = ((lane & 3) ^ ((lane >> 3) & 3)) * 8;
    const u16* gA = Ag + (size_t)(m0 + wv * 16 + srow) * KDIM + scol;
    const u16* gB = Bg + (size_t)(n0 + wv * 16 + srow) * KDIM + scol;
    u16* dA0 = &sAb[(wv * 16) * 32];
    u16* dA1 = &sAb[(wv * 16 + 128) * 32];
    u16* dB  = &sBb[(wv * 16) * 32];

#define SSA(b, p, ki) { gload_lds16(gA + (ki) + (p) * 32,                      dA0 + ((b) * 2 + (p)) * 8192); \
                        gload_lds16(gA + (ki) + (p) * 32 + (size_t)128 * KDIM, dA1 + ((b) * 2 + (p)) * 8192); }
#define SSB(b, p, ki)   gload_lds16(gB + (ki) + (p) * 32,                      dB  + ((b) * 2 + (p)) * 4096);

    const int wm = (wv >> 1) * 64;
    const int wn = (wv & 1) * 64;
    const int fr = lane & 15;
    const int fq = lane >> 4;
    const int fsw = (fq ^ ((fr >> 1) & 3)) * 8;

#define SAF(b, kk, mt) (*(const bf16x8*)&sAb[(((b) * 2 + (kk)) * 256 + wm + (mt) * 16 + fr) * 32 + fsw])
#define SBF(b, kk, nt) (*(const bf16x8*)&sBb[(((b) * 2 + (kk)) * 128 + wn + (nt) * 16 + fr) * 32 + fsw])
#define SMF(mt, nt, xa, xb_) acc[mt][nt] = __builtin_amdgcn_mfma_f32_16x16x32_bf16(xa, xb_, acc[mt][nt], 0, 0, 0)
#define SM8(mA, mB, xA, xB, b0_, b1_, b2_, b3_) \
    SMF(mA, 0, xA, b0_); SMF(mA, 1, xA, b1_); SMF(mA, 2, xA, b2_); SMF(mA, 3, xA, b3_); \
    SMF(mB, 0, xB, b0_); SMF(mB, 1, xB, b1_); SMF(mB, 2, xB, b2_); SMF(mB, 3, xB, b3_);

    f32x4 acc[4][4] = {};
    auto kof = [&](int i) { return i < 16 ? kb0 + i * 64 : kb1 + (i - 16) * 64; };

    {
        const int k0 = kof(0), k1 = kof(1);
        SSB(0, 0, k0); SSA(0, 0, k0); SSB(0, 1, k0); SSA(0, 1, k0);
        SSB(1, 0, k1); SSA(1, 0, k1); SSB(1, 1, k1);
    }
    VM(4);
    BARR;

#define SKQUAD(bb, S1, S2, S3, S4, VW)                                            \
    {                                                                             \
        { S1; }                                                                   \
        {                                                                         \
            bf16x8 b0 = SBF(bb, 0, 0), b1 = SBF(bb, 0, 1),                        \
                   b2 = SBF(bb, 0, 2), b3 = SBF(bb, 0, 3);                        \
            bf16x8 a0 = SAF(bb, 0, 0), a1 = SAF(bb, 0, 1);                        \
            BARR; PRIO1; SM8(0, 1, a0, a1, b0, b1, b2, b3); PRIO0; BARR;          \
            { S2; }                                                               \
            bf16x8 a2 = SAF(bb, 0, 2), a3 = SAF(bb, 0, 3);                        \
            BARR; PRIO1; SM8(2, 3, a2, a3, b0, b1, b2, b3); PRIO0; BARR;          \
        }                                                                         \
        { S3; }                                                                   \
        {                                                                         \
            bf16x8 b0 = SBF(bb, 1, 0), b1 = SBF(bb, 1, 1),                        \
                   b2 = SBF(bb, 1, 2), b3 = SBF(bb, 1, 3);                        \
            bf16x8 a0 = SAF(bb, 1, 0), a1 = SAF(bb, 1, 1);                        \
            BARR; PRIO1; SM8(0, 1, a0, a1, b0, b1, b2, b3); PRIO0; BARR;          \
            { S4; }                                                               \
            bf16x8 a2 = SAF(bb, 1, 2), a3 = SAF(bb, 1, 3);                        \
            BARR; PRIO1; SM8(2, 3, a2, a3, b0, b1, b2, b3); PRIO0;                \
            { VW; }                                                               \
            BARR;                                                                 \
        }                                                                         \
    }

    for (int i = 0; i < 16; ++i) {
        const bool nl  = (i + 1 < 16);
        const int  kn1 = kof(2 * i + 1);
        const int  kn2 = nl ? kof(2 * i + 2) : 0;
        const int  kn3 = nl ? kof(2 * i + 3) : 0;
        SKQUAD(0,
               SSA(1, 1, kn1),
               if (nl) { SSB(0, 0, kn2); },
               if (nl) { SSA(0, 0, kn2); },
               if (nl) { SSB(0, 1, kn2); },
               if (nl) { VM(4); } else { VM(0); });
        SKQUAD(1,
               if (nl) { SSA(0, 1, kn2); },
               if (nl) { SSB(1, 0, kn3); },
               if (nl) { SSA(1, 0, kn3); },
               if (nl) { SSB(1, 1, kn3); },
               if (nl) { VM(4); });
    }

#pragma unroll
    for (int nt = 0; nt < 4; ++nt) {
        int n = n0 + wn + nt * 16 + fr;
        float bv = bias[n];
#pragma unroll
        for (int mt = 0; mt < 4; ++mt) {
            int m = m0 + wm + mt * 16 + fq * 4;
#pragma unroll
            for (int r = 0; r < 4; ++r)
                C[(size_t)(m + r) * NDIM + n] = acc[mt][nt][r] + bv;
        }
    }
}

// ======== full path: BM=256, BN=64, 48 kt linear; 8-MFMA clusters (4A x 2B) ========
// Stage units/iter: Q1-T1 = A1(t+1)+B01(t+1) [3 gloads], Q1-T2 = A0(t+2) [2],
// Q2-T1 = B01(t+2)+A1(t+2) [3], Q2-T2 = A0(t+3) [2]; VM(2) at each quad close.
// B01 = both 32-k planes in one unit: waves 0-3 stage plane 0, waves 4-7 plane 1
// (16 rows/wave). Every unit lands after a barrier following all reads of its plane.
__device__ __forceinline__ void gemm_full(const u16* __restrict__ Ag, const u16* __restrict__ Bg,
                                          const float* __restrict__ bias, float* __restrict__ C,
                                          u16* smem, int m0, int n0, int tid) {
    u16* sAb = smem;             // 4 planes x 256 x 32
    u16* sB6 = smem + 32768;     // 4 planes x  64 x 32
    const int wv = tid >> 6, lane = tid & 63;
    const int srow = lane >> 2;
    const int scol = ((lane & 3) ^ ((lane >> 3) & 3)) * 8;
    const u16* gA = Ag + (size_t)(m0 + wv * 16 + srow) * KDIM + scol;
    const u16* gB = Bg + (size_t)(n0 + (wv & 3) * 16 + srow) * KDIM + scol;
    u16* dA0 = &sAb[(wv * 16) * 32];
    u16* dA1 = &sAb[(wv * 16 + 128) * 32];
    u16* dB6 = &sB6[((wv & 3) * 16) * 32];
    const int bp = wv >> 2;      // B plane this wave stages

#define FSA(b, p, ki) { gload_lds16(gA + (ki) + (p) * 32,                      dA0 + ((b) * 2 + (p)) * 8192); \
                        gload_lds16(gA + (ki) + (p) * 32 + (size_t)128 * KDIM, dA1 + ((b) * 2 + (p)) * 8192); }
#define FSB(b, ki)      gload_lds16(gB + (ki) + bp * 32,                       dB6 + ((b) * 2 + bp) * 2048);

    const int wm = (wv >> 1) * 64;
    const int wn = (wv & 1) * 32;
    const int fr = lane & 15;
    const int fq = lane >> 4;
    const int fsw = (fq ^ ((fr >> 1) & 3)) * 8;

#define FAF(b, kk, mt) (*(const bf16x8*)&sAb[(((b) * 2 + (kk)) * 256 + wm + (mt) * 16 + fr) * 32 + fsw])
#define FBF(b, kk, nt) (*(const bf16x8*)&sB6[(((b) * 2 + (kk)) * 64  + wn + (nt) * 16 + fr) * 32 + fsw])
#define FMF(mt, nt, xa, xb_) acc[mt][nt] = __builtin_amdgcn_mfma_f32_16x16x32_bf16(xa, xb_, acc[mt][nt], 0, 0, 0)
#define FM8(a0_, a1_, a2_, a3_, b0_, b1_) \
    FMF(0, 0, a0_, b0_); FMF(0, 1, a0_, b1_); FMF(1, 0, a1_, b0_); FMF(1, 1, a1_, b1_); \
    FMF(2, 0, a2_, b0_); FMF(2, 1, a2_, b1_); FMF(3, 0, a3_, b0_); FMF(3, 1, a3_, b1_);

    f32x4 acc[4][2] = {};

    // prologue: tile0 {B01, A0, A1}, tile1 {A0}; tile1's A1+B01 come at first Q1-T1
    FSB(0, 0); FSA(0, 0, 0); FSA(0, 1, 0); FSA(1, 0, 64);
    VM(2);       // 7 outstanding -> oldest 5 (= tile0) done
    BARR;

#define FQUAD(bb, T1, T2, VW)                                                     \
    {                                                                             \
        { T1; }                                                                   \
        {                                                                         \
            bf16x8 a0 = FAF(bb, 0, 0), a1 = FAF(bb, 0, 1),                        \
                   a2 = FAF(bb, 0, 2), a3 = FAF(bb, 0, 3);                        \
            bf16x8 b0 = FBF(bb, 0, 0), b1 = FBF(bb, 0, 1);                        \
            BARR; PRIO1; FM8(a0, a1, a2, a3, b0, b1); PRIO0; BARR;                \
        }                                                                         \
        { T2; }                                                                   \
        {                                                                         \
            bf16x8 a0 = FAF(bb, 1, 0), a1 = FAF(bb, 1, 1),                        \
                   a2 = FAF(bb, 1, 2), a3 = FAF(bb, 1, 3);                        \
            bf16x8 b0 = FBF(bb, 1, 0), b1 = FBF(bb, 1, 1);                        \
            BARR; PRIO1; FM8(a0, a1, a2, a3, b0, b1); PRIO0;                      \
            { VW; }                                                               \
            BARR;                                                                 \
        }                                                                         \
    }

    for (int i = 0; i < 24; ++i) {
        const bool nl = (i + 1 < 24);
        const int k1 = (2 * i + 1) * 64;
        const int k2 = nl ? (2 * i + 2) * 64 : 0;
        const int k3 = nl ? (2 * i + 3) * 64 : 0;
        // tile t (buf0): T1 -> buf1 (prev consumed), T2 -> buf0 A plane0 (kk0 reads done)
        FQUAD(0,
              { FSA(1, 1, k1); FSB(1, k1); },
              { if (nl) { FSA(0, 0, k2); } },
              { if (nl) { VM(2); } else { VM(0); } });
        // tile t+1 (buf1): T1 -> buf0 (t consumed), T2 -> buf1 A plane0 (kk0 reads done)
        FQUAD(1,
              { if (nl) { FSB(0, k2); FSA(0, 1, k2); } },
              { if (nl) { FSA(1, 0, k3); } },
              { if (nl) { VM(2); } else { VM(0); } });
    }

#pragma unroll
    for (int nt = 0; nt < 2; ++nt) {
        int n = n0 + wn + nt * 16 + fr;
        float bv = bias[n];
#pragma unroll
        for (int mt = 0; mt < 4; ++mt) {
            int m = m0 + wm + mt * 16 + fq * 4;
#pragma unroll
            for (int r = 0; r < 4; ++r)
                C[(size_t)(m + r) * NDIM + n] = acc[mt][nt][r] + bv;
        }
    }
}

__global__ void __launch_bounds__(512, 2)
gemm_kernel(const u16* __restrict__ Ag, const u16* __restrict__ Bg,
            const float* __restrict__ bias, float* __restrict__ C) {
    extern __shared__ u16 smem[];    // 96 KiB alloc (skip path uses all; full path 80 KiB)
    const int tid = threadIdx.x;
    const int bik = blockIdx.x;
    if (bik >= 128 && bik < 384) {
        // skips: s<128 -> cls0 (bx 0..3), else cls2 (bx 8..11); by = xcd*4 + l
        const int s    = bik - 128;
        const int half = s >> 7;
        const int t_   = s & 127;
        const int by   = (t_ & 7) * 4 + ((t_ >> 3) & 3);
        const int bx   = (half ? 8 : 0) + (t_ >> 5);
        gemm_skip(Ag, Bg, bias, C, smem, by * 256, bx * 128,
                  half ? 512 : 0, half ? 2048 : 1536, tid);
    } else {
        // fulls: f = 0..255 over (xcd, l, col); n0 = 512 + col*64
        const int f   = bik < 128 ? bik : bik - 256;
        const int by  = (f & 7) * 4 + ((f >> 3) & 3);
        const int col = f >> 5;
        gemm_full(Ag, Bg, bias, C, smem, by * 256, 512 + col * 64, tid);
    }
}

extern "C" void kernel_launch(void* const* d_in, const int* in_sizes, int n_in,
                              void* d_out, int out_size, void* d_ws, size_t ws_size,
                              hipStream_t stream) {
    const float* x    = (const float*)d_in[0];   // [8192][3072]
    const float* w    = (const float*)d_in[1];   // [3072][1536]
    const float* bias = (const float*)d_in[2];   // [1536]
    const float* mask = (const float*)d_in[3];   // [1536][3072]
    float* out = (float*)d_out;                  // [8192][1536]

    u16* xb = (u16*)d_ws;                                   // 50331648 B
    u16* Bt = (u16*)((char*)d_ws + (size_t)50331648);       //  9437184 B

    static bool attr_done = false;
    if (!attr_done) {
        (void)hipFuncSetAttribute((const void*)gemm_kernel,
                                  hipFuncAttributeMaxDynamicSharedMemorySize, 98304);
        attr_done = true;
    }

    prep_kernel<<<NMB + NCVT, 256, 0, stream>>>(w, mask, Bt, (const float4*)x, (ushort4*)xb);
    gemm_kernel<<<512, 512, 98304, stream>>>(xb, Bt, bias, out);
}

// Round 9
// 256.039 us; speedup vs baseline: 1.0294x; 1.0294x over previous
//
#include <hip/hip_runtime.h>
#include <stdint.h>

#define MDIM 8192
#define NDIM 1536
#define KDIM 3072

#define BM 256
#define BN 128
#define BK 64            // one K-tile = two 32-k planes in the proven swizzled layout
#define NGB ((MDIM / BM) * (NDIM / BN))   // 384 blocks

#define NMB ((KDIM / 64) * (NDIM / 64))
#define NCVT ((MDIM * KDIM / 4) / 256)

typedef unsigned short u16;
typedef float  f32x4  __attribute__((ext_vector_type(4)));
typedef __bf16 bf16x8 __attribute__((ext_vector_type(8)));

__device__ __forceinline__ u16 f2bf(float f) {
    union { float f; unsigned int u; } v; v.f = f;
    unsigned int u = v.u;
    return (u16)((u + 0x7fffu + ((u >> 16) & 1u)) >> 16);  // RNE
}

// ---------------- fused prep (R0/R2-proven): make_b blocks, then cvt_x blocks ----------------
__global__ void prep_kernel(const float* __restrict__ w, const float* __restrict__ mask,
                            u16* __restrict__ Bt,
                            const float4* __restrict__ x, ushort4* __restrict__ xb) {
    const int t = threadIdx.x;
    if (blockIdx.x < NMB) {
        __shared__ float sw[64][65];
        const int kb = blockIdx.x % (KDIM / 64);
        const int nb = blockIdx.x / (KDIM / 64);
        const int k0 = kb * 64, n0 = nb * 64;
        {
            const int c4 = t & 15;
            const int r  = t >> 4;
#pragma unroll
            for (int rr = 0; rr < 4; ++rr) {
                int row = rr * 16 + r;
                float4 v = *(const float4*)&w[(size_t)(k0 + row) * NDIM + n0 + c4 * 4];
                sw[row][c4 * 4 + 0] = v.x;
                sw[row][c4 * 4 + 1] = v.y;
                sw[row][c4 * 4 + 2] = v.z;
                sw[row][c4 * 4 + 3] = v.w;
            }
        }
        __syncthreads();
        {
            const int n  = t >> 2;
            const int ks = (t & 3) * 16;
#pragma unroll
            for (int j = 0; j < 4; ++j) {
                int k = ks + j * 4;
                float4 mv = *(const float4*)&mask[(size_t)(n0 + n) * KDIM + k0 + k];
                ushort4 o;
                o.x = f2bf(mv.x * sw[k + 0][n]);
                o.y = f2bf(mv.y * sw[k + 1][n]);
                o.z = f2bf(mv.z * sw[k + 2][n]);
                o.w = f2bf(mv.w * sw[k + 3][n]);
                *(ushort4*)&Bt[(size_t)(n0 + n) * KDIM + k0 + k] = o;
            }
        }
    } else {
        int i = (blockIdx.x - NMB) * 256 + t;
        float4 v = x[i];
        ushort4 o;
        o.x = f2bf(v.x); o.y = f2bf(v.y); o.z = f2bf(v.z); o.w = f2bf(v.w);
        xb[i] = o;
    }
}

// ---------------- GEMM: 8-phase counted-vmcnt template (T3+T4+T5), 256x128, 8 waves ----------------
// K-skip (exact, 64-aligned): cls0 (n<512): k in [0,1024)u[1536,2560); cls1: full;
// cls2 (n>=1024): [512,1536)u[2048,3072). Dispatch: 128 full-K blocks first, 256 skip
// blocks backfill (skip-CUs run 32+32 tiles vs full-CU 48). XCD banding by = xcd*4+l.
// Staging: 4 units/tile {B0:1, A0:2, B1:1, A1:2 gloads}, 1 unit/phase, each unit targets
// a plane fully consumed >=1 barrier earlier. vmcnt(4) before phase-4/8 closing barriers
// (= loads issued after the tile about to be computed). Raw s_barrier (no vmcnt-0 drain).
// Session ledger: balance to the 56e ideal is PROVEN STUCK (R6 split-K sync -2x;
// R7 128^2 2/CU cluster-shrink -24%; R8 BN=64 class -20%/unit). 64e makespan stands.
__device__ __forceinline__ void gload_lds16(const void* g, void* l) {
    __builtin_amdgcn_global_load_lds(
        (const __attribute__((address_space(1))) unsigned int*)g,
        (__attribute__((address_space(3))) unsigned int*)l, 16, 0, 0);
}

#define BARR  __builtin_amdgcn_s_barrier()
#define PRIO1 __builtin_amdgcn_s_setprio(1)
#define PRIO0 __builtin_amdgcn_s_setprio(0)
#define VM(n) asm volatile("s_waitcnt vmcnt(" #n ")" ::: "memory")

__global__ void __launch_bounds__(512, 2)
gemm_kernel(const u16* __restrict__ Ag,  // [M][K] bf16
            const u16* __restrict__ Bg,  // [N][K] bf16
            const float* __restrict__ bias,
            float* __restrict__ C) {     // [M][N] fp32
    extern __shared__ u16 smem[];        // 96 KiB: A 64K (4 planes x 256 x 32), B 32K
    u16* sAb = smem;                     // [(buf*2+plane)][256][32]
    u16* sBb = smem + 32768;             // [(buf*2+plane)][128][32]

    const int tid  = threadIdx.x;
    const int wv   = tid >> 6;           // 0..7
    const int lane = tid & 63;

    // ordering: bik 0..127 = full-K (bx 4..7), 128..383 = skip tiles; XCD r -> by in [4r,4r+4)
    const int bik = blockIdx.x;
    int bx, by;
    if (bik < 128) {
        by = (bik & 7) * 4 + ((bik >> 3) & 3);
        bx = 4 + (bik >> 5);
    } else {
        const int s = bik - 128;
        by = (s & 7) * 4 + ((s >> 3) & 3);
        const int r = s >> 5;            // 0..7
        bx = r < 4 ? r : r + 4;
    }
    const int m0 = by * BM, n0 = bx * BN;
    const int cls = bx >> 2;             // 0,1,2

    int ksplit, kb0, kb1, NT;
    if (cls == 1)      { ksplit = 48; kb0 = 0;   kb1 = 0;    NT = 48; }
    else if (cls == 0) { ksplit = 16; kb0 = 0;   kb1 = 1536; NT = 32; }
    else               { ksplit = 16; kb0 = 512; kb1 = 2048; NT = 32; }
    const int NI = NT >> 1;
    auto kof = [&](int i) { return i < ksplit ? kb0 + i * 64 : kb1 + (i - ksplit) * 64; };

    // staging addressing (proven plane-swizzle: source chunk xor, linear LDS dest)
    const int srow = lane >> 2;
    const int scol = ((lane & 3) ^ ((lane >> 3) & 3)) * 8;
    const u16* gA = Ag + (size_t)(m0 + wv * 16 + srow) * KDIM + scol;
    const u16* gB = Bg + (size_t)(n0 + wv * 16 + srow) * KDIM + scol;
    u16* dA0 = &sAb[(wv * 16) * 32];
    u16* dA1 = &sAb[(wv * 16 + 128) * 32];
    u16* dB  = &sBb[(wv * 16) * 32];

#define SA(b, p, ki) { gload_lds16(gA + (ki) + (p) * 32,                     dA0 + ((b) * 2 + (p)) * 8192); \
                       gload_lds16(gA + (ki) + (p) * 32 + (size_t)128 * KDIM, dA1 + ((b) * 2 + (p)) * 8192); }
#define SB(b, p, ki)   gload_lds16(gB + (ki) + (p) * 32,                     dB  + ((b) * 2 + (p)) * 4096);

    // fragment addressing (proven swizzle)
    const int wm = (wv >> 1) * 64;
    const int wn = (wv & 1) * 64;
    const int fr = lane & 15;
    const int fq = lane >> 4;
    const int fsw = (fq ^ ((fr >> 1) & 3)) * 8;

#define AFRAG(b, kk, mt) (*(const bf16x8*)&sAb[(((b) * 2 + (kk)) * 256 + wm + (mt) * 16 + fr) * 32 + fsw])
#define BFRAG(b, kk, nt) (*(const bf16x8*)&sBb[(((b) * 2 + (kk)) * 128 + wn + (nt) * 16 + fr) * 32 + fsw])
#define MF(mt, nt, xa, xb_) acc[mt][nt] = __builtin_amdgcn_mfma_f32_16x16x32_bf16(xa, xb_, acc[mt][nt], 0, 0, 0)
#define M8(mA, mB, xA, xB, b0_, b1_, b2_, b3_) \
    MF(mA, 0, xA, b0_); MF(mA, 1, xA, b1_); MF(mA, 2, xA, b2_); MF(mA, 3, xA, b3_); \
    MF(mB, 0, xB, b0_); MF(mB, 1, xB, b1_); MF(mB, 2, xB, b2_); MF(mB, 3, xB, b3_);

    f32x4 acc[4][4] = {};

    // prologue: tile0 complete {B0,A0,B1,A1}, tile1 partial {B0,A0,B1}; tile1.A1 comes at P1
    {
        const int k0 = kof(0), k1 = kof(1);
        SB(0, 0, k0); SA(0, 0, k0); SB(0, 1, k0); SA(0, 1, k0);
        SB(1, 0, k1); SA(1, 0, k1); SB(1, 1, k1);
    }
    VM(4);       // tile0's 6 done (only tile1's 4 newer)
    BARR;

    // one quad = 4 phases over one buffer; S1..S4 = per-phase stage units, VW = counted wait
#define QUAD(bb, S1, S2, S3, S4, VW)                                              \
    {                                                                             \
        { S1; }                                                                   \
        {                                                                         \
            bf16x8 b0 = BFRAG(bb, 0, 0), b1 = BFRAG(bb, 0, 1),                    \
                   b2 = BFRAG(bb, 0, 2), b3 = BFRAG(bb, 0, 3);                    \
            bf16x8 a0 = AFRAG(bb, 0, 0), a1 = AFRAG(bb, 0, 1);                    \
            BARR; PRIO1; M8(0, 1, a0, a1, b0, b1, b2, b3); PRIO0; BARR;           \
            { S2; }                                                               \
            bf16x8 a2 = AFRAG(bb, 0, 2), a3 = AFRAG(bb, 0, 3);                    \
            BARR; PRIO1; M8(2, 3, a2, a3, b0, b1, b2, b3); PRIO0; BARR;           \
        }                                                                         \
        { S3; }                                                                   \
        {                                                                         \
            bf16x8 b0 = BFRAG(bb, 1, 0), b1 = BFRAG(bb, 1, 1),                    \
                   b2 = BFRAG(bb, 1, 2), b3 = BFRAG(bb, 1, 3);                    \
            bf16x8 a0 = AFRAG(bb, 1, 0), a1 = AFRAG(bb, 1, 1);                    \
            BARR; PRIO1; M8(0, 1, a0, a1, b0, b1, b2, b3); PRIO0; BARR;           \
            { S4; }                                                               \
            bf16x8 a2 = AFRAG(bb, 1, 2), a3 = AFRAG(bb, 1, 3);                    \
            BARR; PRIO1; M8(2, 3, a2, a3, b0, b1, b2, b3); PRIO0;                 \
            { VW; }                                                               \
            BARR;                                                                 \
        }                                                                         \
    }

    for (int i = 0; i < NI; ++i) {
        const bool nl  = (i + 1 < NI);
        const int  kn1 = kof(2 * i + 1);
        const int  kn2 = nl ? kof(2 * i + 2) : 0;
        const int  kn3 = nl ? kof(2 * i + 3) : 0;

        // phases 1-4: tile t (buf0); stage t+1.A1, then t+2.{B0,A0,B1} -> buf0
        QUAD(0,
             SA(1, 1, kn1),
             if (nl) { SB(0, 0, kn2); },
             if (nl) { SA(0, 0, kn2); },
             if (nl) { SB(0, 1, kn2); },
             if (nl) { VM(4); } else { VM(0); });

        // phases 5-8: tile t+1 (buf1); stage t+2.A1 -> buf0, then t+3.{B0,A0,B1} -> buf1
        QUAD(1,
             if (nl) { SA(0, 1, kn2); },
             if (nl) { SB(1, 0, kn3); },
             if (nl) { SA(1, 0, kn3); },
             if (nl) { SB(1, 1, kn3); },
             if (nl) { VM(4); });
    }

    // epilogue: C/D layout col = lane&15, row = (lane>>4)*4 + reg  [m89-verified]
#pragma unroll
    for (int nt = 0; nt < 4; ++nt) {
        int n = n0 + wn + nt * 16 + fr;
        float bv = bias[n];
#pragma unroll
        for (int mt = 0; mt < 4; ++mt) {
            int m = m0 + wm + mt * 16 + fq * 4;
#pragma unroll
            for (int r = 0; r < 4; ++r)
                C[(size_t)(m + r) * NDIM + n] = acc[mt][nt][r] + bv;
        }
    }
}

extern "C" void kernel_launch(void* const* d_in, const int* in_sizes, int n_in,
                              void* d_out, int out_size, void* d_ws, size_t ws_size,
                              hipStream_t stream) {
    const float* x    = (const float*)d_in[0];   // [8192][3072]
    const float* w    = (const float*)d_in[1];   // [3072][1536]
    const float* bias = (const float*)d_in[2];   // [1536]
    const float* mask = (const float*)d_in[3];   // [1536][3072]
    float* out = (float*)d_out;                  // [8192][1536]

    u16* xb = (u16*)d_ws;                                   // 50331648 B
    u16* Bt = (u16*)((char*)d_ws + (size_t)50331648);       //  9437184 B

    static bool attr_done = false;
    if (!attr_done) {
        (void)hipFuncSetAttribute((const void*)gemm_kernel,
                                  hipFuncAttributeMaxDynamicSharedMemorySize, 98304);
        attr_done = true;
    }

    prep_kernel<<<NMB + NCVT, 256, 0, stream>>>(w, mask, Bt, (const float4*)x, (ushort4*)xb);
    gemm_kernel<<<NGB, 512, 98304, stream>>>(xb, Bt, bias, out);
}